// Round 3
// baseline (947.403 us; speedup 1.0000x reference)
//
#include <hip/hip_runtime.h>
#include <stdint.h>

// DCGRU cell on MI355X — round 3: 256^2-tile 8-wave counted-vmcnt diffusion GEMM.
//
// Buffers (d_ws, ~178 MB, same layout as round 2):
//   Abf  [4096][2048] bf16   supports stacked [A0;A1]
//   Xbf  [4224][2048] bf16   X rows (b*66+c); rows 2..65 overwritten with r*hx
//   Y1   [4224][4096] bf16   x1 (both supports)
//   Ht   [131072][352] bf16  packed H^T: row m=(b*2048+n), col K = slot*66+c
//   Ubuf [64*64*2048] bf16   u gate
//   Wt_ru/Wt_c [128][352] bf16

typedef unsigned short ushort_t;
typedef __attribute__((ext_vector_type(8))) __bf16 bf16x8;
typedef __attribute__((ext_vector_type(4))) float f32x4;

#define KP 352
#define MROWS 131072
#define MREAL 4224

__device__ __forceinline__ ushort_t f2bf(float f) {
  union { float f; uint32_t u; } v; v.f = f;
  uint32_t r = v.u + 0x7FFFu + ((v.u >> 16) & 1u);   // RNE
  return (ushort_t)(r >> 16);
}
__device__ __forceinline__ float bf2f(ushort_t u) {
  union { uint32_t u; float f; } v; v.u = ((uint32_t)u) << 16;
  return v.f;
}

__device__ __forceinline__ void gl_lds16(const void* g, void* l) {
  __builtin_amdgcn_global_load_lds(
      (const __attribute__((address_space(1))) void*)g,
      (__attribute__((address_space(3))) void*)l, 16, 0, 0);
}

// ---------------- prep kernels ----------------

__global__ void k_cast(const float* __restrict__ src, ushort_t* __restrict__ dst, int n) {
  for (int i = (blockIdx.x * 256 + threadIdx.x) * 4; i < n; i += gridDim.x * 256 * 4) {
    float4 v = *(const float4*)(src + i);
    ushort4 r;
    r.x = f2bf(v.x); r.y = f2bf(v.y); r.z = f2bf(v.z); r.w = f2bf(v.w);
    *(ushort4*)(dst + i) = r;
  }
}

__global__ void k_build_X(const float* __restrict__ inputs, const float* __restrict__ hx,
                          ushort_t* __restrict__ Xbf) {
  int r = blockIdx.x;
  int b = r / 66, c = r - b * 66;
  const float* src = (c < 2) ? (inputs + ((size_t)b * 2 + c) * 2048)
                             : (hx + ((size_t)b * 64 + (c - 2)) * 2048);
  ushort_t* d1 = Xbf + (size_t)r * 2048;
  for (int n = threadIdx.x * 4; n < 2048; n += 256 * 4) {
    float4 v = *(const float4*)(src + n);
    ushort4 rr;
    rr.x = f2bf(v.x); rr.y = f2bf(v.y); rr.z = f2bf(v.z); rr.w = f2bf(v.w);
    *(ushort4*)(d1 + n) = rr;
  }
}

__global__ void k_pack_W(const float* __restrict__ W, int O, ushort_t* __restrict__ Wt) {
  int o = blockIdx.x;
  for (int k = threadIdx.x; k < KP; k += 256) {
    float v = (k < 330 && o < O) ? W[(size_t)k * O + o] : 0.f;
    Wt[(size_t)o * KP + k] = f2bf(v);
  }
}

// Ht[(b*2048+n)][0..66) = Xbf[(b*66+c)][n]. grid (16, 64)
__global__ __launch_bounds__(256) void k_trans_slot0(const ushort_t* __restrict__ Xbf,
                                                     ushort_t* __restrict__ Ht) {
  __shared__ ushort_t t[66 * 136];
  const int tid = threadIdx.x;
  const int b = blockIdx.y;
  const int n0 = blockIdx.x * 128;
  for (int idx = tid; idx < 66 * 16; idx += 256) {
    int c = idx >> 4, seg = idx & 15;
    bf16x8 v = *(const bf16x8*)&Xbf[((size_t)b * 66 + c) * 2048 + n0 + seg * 8];
    *(bf16x8*)&t[c * 136 + seg * 8] = v;
  }
  __syncthreads();
  for (int idx = tid; idx < 128 * 66; idx += 256) {
    int nn = idx / 66, c = idx - nn * 66;
    Ht[((size_t)b * 2048 + n0 + nn) * KP + c] = t[c * 136 + nn];
  }
}

// ---------------- 256^2-tile 8-wave diffusion GEMM ----------------
// C[r,m] = sum_k A[r,k]*B[m,k] over K=2048 (BK=64, NT=32 K-tiles).
// MODE 0: writes Y1[r][m] and Ht slot (1+2g) = bf16(C).
// MODE 1: A offset g*2048; Ht slot (2+2g) = bf16(2*C - Xres[r][m&2047]).
// Schedule: 4 phases/K-tile; barriers+vmcnt(4) at ph1/ph3 only; stage one
// 16KB chunk per phase into the other LDS buffer (pre-swizzled source).
template <int MODE>
__global__ __launch_bounds__(512, 2) void gemm_bt(
    const ushort_t* __restrict__ Aop, int lda,
    const ushort_t* __restrict__ Bop,
    const ushort_t* __restrict__ Xres,
    ushort_t* __restrict__ Y1out,
    ushort_t* __restrict__ Ht) {
  __shared__ char smem[131072];
  const int tid = threadIdx.x;
  const int l = tid & 63;
  const int w = tid >> 6;
  const int wr = w >> 2, wc = w & 3;      // wave grid 2M x 4N, wave tile 128x64
  const int lr = l & 15, lk = l >> 4;

  // XCD-aware block swizzle: 272 = 8 XCD * 34
  const int bid = blockIdx.x;
  const int swz = (bid & 7) * 34 + (bid >> 3);
  const int mb = swz % 17, nb = swz / 17;
  const int r0 = mb * 256, m0 = nb * 256;
  const int g = m0 >> 11;
  if (MODE == 1) Aop += (size_t)g * 2048;

  // staging: issue order per K-tile = A-k0(2), B-k0(2), A-k1(2), B-k1(2)
  const ushort_t* gsrc[8];
  int ldst[8];
#pragma unroll
  for (int ks = 0; ks < 2; ++ks)
#pragma unroll
    for (int op = 0; op < 2; ++op)
#pragma unroll
      for (int j = 0; j < 2; ++j) {
        const int e = ks * 4 + op * 2 + j;
        const int id = ks * 1024 + j * 512 + tid;
        const int rem = id & 1023;
        const int row = rem >> 2, s = rem & 3;
        const int koff = ks * 32 + ((s ^ ((row >> 1) & 3)) << 3);  // pre-swizzled src
        if (op == 0) { gsrc[e] = Aop + (size_t)(r0 + row) * lda + koff; ldst[e] = id * 16; }
        else         { gsrc[e] = Bop + (size_t)(m0 + row) * 2048 + koff; ldst[e] = 32768 + id * 16; }
      }

  // swizzled lane read offset (slot ^= (row>>1)&3; row%16 == lr here)
  const int laneA = lr * 64 + ((lk ^ ((lr >> 1) & 3)) << 4);
  const int aBase = wr * 8192 + laneA;             // A region
  const int bBase = 32768 + wc * 4096 + laneA;     // B region

  f32x4 acc[8][4];
  const f32x4 zero = {0.f, 0.f, 0.f, 0.f};
#pragma unroll
  for (int mi = 0; mi < 8; ++mi)
#pragma unroll
    for (int ni = 0; ni < 4; ++ni) acc[mi][ni] = zero;

  // prologue: stage kt=0 into buf0
#pragma unroll
  for (int e = 0; e < 8; ++e) gl_lds16(gsrc[e], smem + ldst[e]);

  const int NT = 32;
  for (int kt = 0; kt < NT; ++kt) {
    const int cur = (kt & 1) << 16;
    const int nxt = cur ^ 65536;
    const int knext = (kt + 1) * 64;
    const bool notlast = (kt + 1 < NT);
    bf16x8 bv[4];

    // ---- phase 1: ks=0, mi 0..3 ----
    asm volatile("s_waitcnt vmcnt(4)" ::: "memory");
    __builtin_amdgcn_s_barrier();
    __builtin_amdgcn_sched_barrier(0);
    if (notlast) {
      gl_lds16(gsrc[0] + knext, smem + nxt + ldst[0]);
      gl_lds16(gsrc[1] + knext, smem + nxt + ldst[1]);
    }
#pragma unroll
    for (int ni = 0; ni < 4; ++ni)
      bv[ni] = *(const bf16x8*)(smem + cur + bBase + ni * 1024);
    __builtin_amdgcn_s_setprio(1);
#pragma unroll
    for (int mi = 0; mi < 4; ++mi) {
      bf16x8 av = *(const bf16x8*)(smem + cur + aBase + mi * 1024);
#pragma unroll
      for (int ni = 0; ni < 4; ++ni)
        acc[mi][ni] = __builtin_amdgcn_mfma_f32_16x16x32_bf16(av, bv[ni], acc[mi][ni], 0, 0, 0);
    }
    __builtin_amdgcn_s_setprio(0);

    // ---- phase 2: ks=0, mi 4..7 (reuses bv) ----
    if (notlast) {
      gl_lds16(gsrc[2] + knext, smem + nxt + ldst[2]);
      gl_lds16(gsrc[3] + knext, smem + nxt + ldst[3]);
    }
    __builtin_amdgcn_s_setprio(1);
#pragma unroll
    for (int mi = 4; mi < 8; ++mi) {
      bf16x8 av = *(const bf16x8*)(smem + cur + aBase + mi * 1024);
#pragma unroll
      for (int ni = 0; ni < 4; ++ni)
        acc[mi][ni] = __builtin_amdgcn_mfma_f32_16x16x32_bf16(av, bv[ni], acc[mi][ni], 0, 0, 0);
    }
    __builtin_amdgcn_s_setprio(0);

    // ---- phase 3: ks=1, mi 0..3 ----
    if (notlast) asm volatile("s_waitcnt vmcnt(4)" ::: "memory");
    else         asm volatile("s_waitcnt vmcnt(0)" ::: "memory");
    __builtin_amdgcn_s_barrier();
    __builtin_amdgcn_sched_barrier(0);
    if (notlast) {
      gl_lds16(gsrc[4] + knext, smem + nxt + ldst[4]);
      gl_lds16(gsrc[5] + knext, smem + nxt + ldst[5]);
    }
#pragma unroll
    for (int ni = 0; ni < 4; ++ni)
      bv[ni] = *(const bf16x8*)(smem + cur + bBase + 16384 + ni * 1024);
    __builtin_amdgcn_s_setprio(1);
#pragma unroll
    for (int mi = 0; mi < 4; ++mi) {
      bf16x8 av = *(const bf16x8*)(smem + cur + aBase + 16384 + mi * 1024);
#pragma unroll
      for (int ni = 0; ni < 4; ++ni)
        acc[mi][ni] = __builtin_amdgcn_mfma_f32_16x16x32_bf16(av, bv[ni], acc[mi][ni], 0, 0, 0);
    }
    __builtin_amdgcn_s_setprio(0);

    // ---- phase 4: ks=1, mi 4..7 ----
    if (notlast) {
      gl_lds16(gsrc[6] + knext, smem + nxt + ldst[6]);
      gl_lds16(gsrc[7] + knext, smem + nxt + ldst[7]);
    }
    __builtin_amdgcn_s_setprio(1);
#pragma unroll
    for (int mi = 4; mi < 8; ++mi) {
      bf16x8 av = *(const bf16x8*)(smem + cur + aBase + 16384 + mi * 1024);
#pragma unroll
      for (int ni = 0; ni < 4; ++ni)
        acc[mi][ni] = __builtin_amdgcn_mfma_f32_16x16x32_bf16(av, bv[ni], acc[mi][ni], 0, 0, 0);
    }
    __builtin_amdgcn_s_setprio(0);
  }

  // ---------------- epilogue ----------------
  __syncthreads();

  if (MODE == 0) {
#pragma unroll
    for (int mi = 0; mi < 8; ++mi) {
#pragma unroll
      for (int ni = 0; ni < 4; ++ni) {
        const int rw0 = r0 + wr * 128 + mi * 16 + lk * 4;
        const int cg = m0 + wc * 64 + ni * 16 + lr;
#pragma unroll
        for (int j = 0; j < 4; ++j) {
          const int rw = rw0 + j;
          if (rw < MREAL) Y1out[(size_t)rw * 4096 + cg] = f2bf(acc[mi][ni][j]);
        }
      }
    }
  }

  const int slotBase = (MODE == 0 ? 1 : 2) + 2 * g;
  ushort_t* Tw = (ushort_t*)(smem + wr * 33792);  // [128 cols][132 rows]

#pragma unroll 1
  for (int pass = 0; pass < 2; ++pass) {
    __syncthreads();
    if ((wc >> 1) == pass) {
      const int clb = (wc & 1) * 64;
#pragma unroll
      for (int mi = 0; mi < 8; ++mi) {
        const int rl0 = mi * 16 + lk * 4;
#pragma unroll
        for (int ni = 0; ni < 4; ++ni) {
          const int cl = clb + ni * 16 + lr;
          float v0 = acc[mi][ni][0], v1 = acc[mi][ni][1];
          float v2 = acc[mi][ni][2], v3 = acc[mi][ni][3];
          if (MODE == 1) {
            const size_t xb = (size_t)(r0 + wr * 128 + rl0) * 2048 +
                              ((m0 + pass * 128 + cl) & 2047);
            v0 = 2.f * v0 - bf2f(Xres[xb]);
            v1 = 2.f * v1 - bf2f(Xres[xb + 2048]);
            v2 = 2.f * v2 - bf2f(Xres[xb + 4096]);
            v3 = 2.f * v3 - bf2f(Xres[xb + 6144]);
          }
          ushort4 pk;
          pk.x = f2bf(v0); pk.y = f2bf(v1); pk.z = f2bf(v2); pk.w = f2bf(v3);
          *(ushort4*)&Tw[cl * 132 + rl0] = pk;
        }
      }
    }
    __syncthreads();
#pragma unroll 4
    for (int q = 0; q < 64; ++q) {
      const int idx = q * 512 + tid;
      const int sr = idx >> 14, rem = idx & 16383;
      const int mc = rem >> 7, rl = rem & 127;
      const int rg = r0 + sr * 128 + rl;
      if (rg < MREAL) {
        const unsigned bb = (unsigned)rg / 66u;
        const unsigned ch = (unsigned)rg - bb * 66u;
        const int n = (m0 + pass * 128 + mc) & 2047;
        const ushort_t* Ts = (const ushort_t*)(smem + sr * 33792);
        Ht[((size_t)bb * 2048 + n) * KP + slotBase * 66 + ch] = Ts[mc * 132 + rl];
      }
    }
  }
}

// ---------------- MFMA projection GEMM (unchanged, round-2 verified) ----------------
template <int MODE>
__global__ __launch_bounds__(256, 2) void proj_mfma(
    const ushort_t* __restrict__ Ht, const ushort_t* __restrict__ Wt,
    const float* __restrict__ bias, const float* __restrict__ hx,
    ushort_t* __restrict__ Xbf, ushort_t* __restrict__ Ubuf,
    float* __restrict__ out) {
  __shared__ ushort_t smem[128 * 130];
  ushort_t* As = smem;
  ushort_t* Bs = smem + 4096;
  const int tid = threadIdx.x;
  const int l = tid & 63, w = tid >> 6;
  const int wr = w >> 1, wc = w & 1;
  const int lr = l & 15, lk = l >> 4;
  const int bb = blockIdx.x >> 4;
  const int n0 = (blockIdx.x & 15) * 128;
  const size_t m0 = (size_t)bb * 2048 + n0;

  f32x4 acc[4][4];
  const f32x4 zero = {0.f, 0.f, 0.f, 0.f};
#pragma unroll
  for (int mi = 0; mi < 4; mi++)
#pragma unroll
    for (int ni = 0; ni < 4; ni++) acc[mi][ni] = zero;

  const int rowA = l >> 2;
  const int kcol = (l & 3) * 8;

  for (int kk = 0; kk < 11; ++kk) {
    const int k0 = kk * 32;
    const int c0 = 2 * w, c1 = 2 * w + 1;
    gl_lds16(Ht + (m0 + c0 * 16 + rowA) * KP + k0 + kcol, (void*)&As[c0 * 512]);
    gl_lds16(Ht + (m0 + c1 * 16 + rowA) * KP + k0 + kcol, (void*)&As[c1 * 512]);
    gl_lds16(Wt + (size_t)(c0 * 16 + rowA) * KP + k0 + kcol, (void*)&Bs[c0 * 512]);
    gl_lds16(Wt + (size_t)(c1 * 16 + rowA) * KP + k0 + kcol, (void*)&Bs[c1 * 512]);
    __syncthreads();

    bf16x8 af[4], bfv[4];
#pragma unroll
    for (int i = 0; i < 4; i++)
      af[i] = *(const bf16x8*)&As[(wr * 64 + i * 16 + lr) * 32 + lk * 8];
#pragma unroll
    for (int i = 0; i < 4; i++)
      bfv[i] = *(const bf16x8*)&Bs[(wc * 64 + i * 16 + lr) * 32 + lk * 8];
#pragma unroll
    for (int mi = 0; mi < 4; mi++)
#pragma unroll
      for (int ni = 0; ni < 4; ni++)
        acc[mi][ni] = __builtin_amdgcn_mfma_f32_16x16x32_bf16(af[mi], bfv[ni], acc[mi][ni], 0, 0, 0);
    __syncthreads();
  }

#pragma unroll
  for (int mi = 0; mi < 4; mi++) {
#pragma unroll
    for (int ni = 0; ni < 4; ni++) {
      const int rl0 = wr * 64 + mi * 16 + lk * 4;
      const int o = wc * 64 + ni * 16 + lr;
      float bv = (MODE == 0 || o < 64) ? bias[o] : 0.f;
#pragma unroll
      for (int j = 0; j < 4; j++) {
        float v = acc[mi][ni][j] + bv;
        float s;
        if (MODE == 0) s = 1.f / (1.f + expf(-v));
        else           s = tanhf(v);
        smem[o * 130 + rl0 + j] = f2bf(s);
      }
    }
  }
  __syncthreads();

  if (MODE == 0) {
#pragma unroll 4
    for (int j2 = 0; j2 < 64; ++j2) {
      int idx = j2 * 256 + tid;
      int o = idx >> 7, m = idx & 127;
      ushort_t sv = smem[o * 130 + m];
      int n = n0 + m;
      if (o < 64) {
        float s = bf2f(sv);
        float hxv = hx[((size_t)bb * 64 + o) * 2048 + n];
        Xbf[((size_t)bb * 66 + 2 + o) * 2048 + n] = f2bf(s * hxv);
      } else {
        Ubuf[((size_t)bb * 64 + (o - 64)) * 2048 + n] = sv;
      }
    }
  } else {
#pragma unroll 4
    for (int j2 = 0; j2 < 32; ++j2) {
      int idx = j2 * 256 + tid;
      int o = idx >> 7, m = idx & 127;
      float Cv = bf2f(smem[o * 130 + m]);
      int n = n0 + m;
      size_t oi = ((size_t)bb * 64 + o) * 2048 + n;
      float u = bf2f(Ubuf[oi]);
      out[oi] = u * hx[oi] + (1.f - u) * Cv;
    }
  }
}

// ---------------- launcher ----------------

extern "C" void kernel_launch(void* const* d_in, const int* in_sizes, int n_in,
                              void* d_out, int out_size, void* d_ws, size_t ws_size,
                              hipStream_t stream) {
  (void)in_sizes; (void)n_in; (void)out_size; (void)ws_size;
  const float* inputs = (const float*)d_in[0];
  const float* hx     = (const float*)d_in[1];
  const float* s0     = (const float*)d_in[2];
  const float* s1     = (const float*)d_in[3];
  const float* W_ru   = (const float*)d_in[4];
  const float* b_ru   = (const float*)d_in[5];
  const float* W_c    = (const float*)d_in[6];
  const float* b_c    = (const float*)d_in[7];
  float* out = (float*)d_out;

  char* p = (char*)d_ws;
  ushort_t* Abf  = (ushort_t*)p; p += (size_t)4096 * 2048 * 2;    // 16.78 MB
  ushort_t* Xbf  = (ushort_t*)p; p += (size_t)4224 * 2048 * 2;    // 17.30 MB
  ushort_t* Y1   = (ushort_t*)p; p += (size_t)4224 * 4096 * 2;    // 34.60 MB
  ushort_t* Ht   = (ushort_t*)p; p += (size_t)MROWS * KP * 2;     // 92.27 MB
  ushort_t* Ubuf = (ushort_t*)p; p += (size_t)64 * 64 * 2048 * 2; // 16.78 MB
  ushort_t* Wtru = (ushort_t*)p; p += (size_t)128 * KP * 2;       // 90 KB
  ushort_t* Wtc  = (ushort_t*)p; p += (size_t)128 * KP * 2;       // 90 KB

  k_cast<<<1024, 256, 0, stream>>>(s0, Abf, 4194304);
  k_cast<<<1024, 256, 0, stream>>>(s1, Abf + 4194304, 4194304);
  k_build_X<<<4224, 256, 0, stream>>>(inputs, hx, Xbf);
  k_pack_W<<<128, 256, 0, stream>>>(W_ru, 128, Wtru);
  k_pack_W<<<128, 256, 0, stream>>>(W_c, 64, Wtc);

  dim3 gt(16, 64);
  // conv 1
  k_trans_slot0<<<gt, 256, 0, stream>>>(Xbf, Ht);
  gemm_bt<0><<<272, 512, 0, stream>>>(Xbf, 2048, Abf, nullptr, Y1, Ht);
  gemm_bt<1><<<272, 512, 0, stream>>>(Y1, 4096, Abf, Xbf, nullptr, Ht);
  proj_mfma<0><<<1024, 256, 0, stream>>>(Ht, Wtru, b_ru, hx, Xbf, Ubuf, nullptr);
  // conv 2
  k_trans_slot0<<<gt, 256, 0, stream>>>(Xbf, Ht);
  gemm_bt<0><<<272, 512, 0, stream>>>(Xbf, 2048, Abf, nullptr, Y1, Ht);
  gemm_bt<1><<<272, 512, 0, stream>>>(Y1, 4096, Abf, Xbf, nullptr, Ht);
  proj_mfma<1><<<1024, 256, 0, stream>>>(Ht, Wtc, b_c, hx, nullptr, Ubuf, out);
}

// Round 4
// 927.762 us; speedup vs baseline: 1.0212x; 1.0212x over previous
//
#include <hip/hip_runtime.h>
#include <stdint.h>

// DCGRU cell on MI355X — round 4: 256^2-tile 2-phase double-buffered diffusion
// GEMM (m230-V0 structure) + XCD remap + both-sides LDS swizzle.
//
// Buffers (d_ws, ~178 MB, same layout as round 2/3):
//   Abf  [4096][2048] bf16   supports stacked [A0;A1]
//   Xbf  [4224][2048] bf16   X rows (b*66+c); rows 2..65 overwritten with r*hx
//   Y1   [4224][4096] bf16   x1 (both supports)
//   Ht   [131072][352] bf16  packed H^T: row m=(b*2048+n), col K = slot*66+c
//   Ubuf [64*64*2048] bf16   u gate
//   Wt_ru/Wt_c [128][352] bf16

typedef unsigned short ushort_t;
typedef __attribute__((ext_vector_type(8))) __bf16 bf16x8;
typedef __attribute__((ext_vector_type(4))) float f32x4;

#define KP 352
#define MROWS 131072
#define MREAL 4224

__device__ __forceinline__ ushort_t f2bf(float f) {
  union { float f; uint32_t u; } v; v.f = f;
  uint32_t r = v.u + 0x7FFFu + ((v.u >> 16) & 1u);   // RNE
  return (ushort_t)(r >> 16);
}
__device__ __forceinline__ float bf2f(ushort_t u) {
  union { uint32_t u; float f; } v; v.u = ((uint32_t)u) << 16;
  return v.f;
}

__device__ __forceinline__ void gl_lds16(const void* g, void* l) {
  __builtin_amdgcn_global_load_lds(
      (const __attribute__((address_space(1))) void*)g,
      (__attribute__((address_space(3))) void*)l, 16, 0, 0);
}

// ---------------- prep kernels ----------------

__global__ void k_cast(const float* __restrict__ src, ushort_t* __restrict__ dst, int n) {
  for (int i = (blockIdx.x * 256 + threadIdx.x) * 4; i < n; i += gridDim.x * 256 * 4) {
    float4 v = *(const float4*)(src + i);
    ushort4 r;
    r.x = f2bf(v.x); r.y = f2bf(v.y); r.z = f2bf(v.z); r.w = f2bf(v.w);
    *(ushort4*)(dst + i) = r;
  }
}

__global__ void k_build_X(const float* __restrict__ inputs, const float* __restrict__ hx,
                          ushort_t* __restrict__ Xbf) {
  int r = blockIdx.x;
  int b = r / 66, c = r - b * 66;
  const float* src = (c < 2) ? (inputs + ((size_t)b * 2 + c) * 2048)
                             : (hx + ((size_t)b * 64 + (c - 2)) * 2048);
  ushort_t* d1 = Xbf + (size_t)r * 2048;
  for (int n = threadIdx.x * 4; n < 2048; n += 256 * 4) {
    float4 v = *(const float4*)(src + n);
    ushort4 rr;
    rr.x = f2bf(v.x); rr.y = f2bf(v.y); rr.z = f2bf(v.z); rr.w = f2bf(v.w);
    *(ushort4*)(d1 + n) = rr;
  }
}

__global__ void k_pack_W(const float* __restrict__ W, int O, ushort_t* __restrict__ Wt) {
  int o = blockIdx.x;
  for (int k = threadIdx.x; k < KP; k += 256) {
    float v = (k < 330 && o < O) ? W[(size_t)k * O + o] : 0.f;
    Wt[(size_t)o * KP + k] = f2bf(v);
  }
}

// Ht[(b*2048+n)][0..66) = Xbf[(b*66+c)][n]. grid (16, 64)
__global__ __launch_bounds__(256) void k_trans_slot0(const ushort_t* __restrict__ Xbf,
                                                     ushort_t* __restrict__ Ht) {
  __shared__ ushort_t t[66 * 136];
  const int tid = threadIdx.x;
  const int b = blockIdx.y;
  const int n0 = blockIdx.x * 128;
  for (int idx = tid; idx < 66 * 16; idx += 256) {
    int c = idx >> 4, seg = idx & 15;
    bf16x8 v = *(const bf16x8*)&Xbf[((size_t)b * 66 + c) * 2048 + n0 + seg * 8];
    *(bf16x8*)&t[c * 136 + seg * 8] = v;
  }
  __syncthreads();
  for (int idx = tid; idx < 128 * 66; idx += 256) {
    int nn = idx / 66, c = idx - nn * 66;
    Ht[((size_t)b * 2048 + n0 + nn) * KP + c] = t[c * 136 + nn];
  }
}

// ---------------- 256^2-tile 2-phase diffusion GEMM ----------------
// C[r,m] = sum_k A[r,k]*B[m,k] over K=2048 (BK=64, 32 K-tiles).
// MODE 0: writes Y1[r][m] and Ht slot (1+2g) = bf16(C).
// MODE 1: A offset g*2048; Ht slot (2+2g) = bf16(2*C - Xres[r][m&2047]).
// Double-buffered LDS (2 x 64KB). One __syncthreads per K-tile; stage for
// kt+1 issued BEFORE compute of kt so the barrier's vmcnt drain is covered
// by the MFMA phase. LDS layout: [256 rows][8 x 16B k-slots], slot
// pre-swizzled at the global source: slot_stored = s, contains global slot
// s ^ ((row>>1)&7); reads XOR with the same mask (both-sides involution).
template <int MODE>
__global__ __launch_bounds__(512, 2) void gemm_bt(
    const ushort_t* __restrict__ Aop, int lda,
    const ushort_t* __restrict__ Bop,
    const ushort_t* __restrict__ Xres,
    ushort_t* __restrict__ Y1out,
    ushort_t* __restrict__ Ht) {
  __shared__ char smem[131072];
  const int tid = threadIdx.x;
  const int l = tid & 63;
  const int w = tid >> 6;
  const int wr = w >> 2, wc = w & 3;      // wave grid 2M x 4N; wave tile 128x64
  const int lr = l & 15, lk = l >> 4;

  // XCD-aware remap: 272 = 8 XCD * 34; each XCD gets 17 mb x 2 nb (B-panels
  // L2-resident, A streamed once per XCD) — round-3-measured FETCH 152 MB.
  const int bid = blockIdx.x;
  const int swz = (bid & 7) * 34 + (bid >> 3);
  const int mb = swz % 17, nb = swz / 17;
  const int r0 = mb * 256, m0 = nb * 256;
  const int g = m0 >> 11;
  if (MODE == 1) Aop += (size_t)g * 2048;

  // staging lane constants: chunk e covers rows e*64..e*64+63 of the 256-row
  // tile; 8 threads per row, 16B each; dest is linear (uniform + lane*16).
  const int srow = tid >> 3;                                  // 0..63
  const int koffl = (((tid & 7) ^ ((tid >> 4) & 7)) << 3);    // pre-swizzled
  const ushort_t* pA = Aop + (size_t)(r0 + srow) * lda + koffl;
  const ushort_t* pB = Bop + (size_t)(m0 + srow) * 2048 + koffl;
  const int ldsOff = tid * 16;

  // read lane constants
  const int laneSwz = (lr >> 1) & 7;
  const int aRow = wr * 16384 + lr * 128;           // + mi*2048 + slot*16
  const int bRow = 32768 + wc * 8192 + lr * 128;    // + ni*2048 + slot*16

  f32x4 acc[8][4];
  const f32x4 zero = {0.f, 0.f, 0.f, 0.f};
#pragma unroll
  for (int mi = 0; mi < 8; ++mi)
#pragma unroll
    for (int ni = 0; ni < 4; ++ni) acc[mi][ni] = zero;

  // prologue: stage kt=0 into buf0
#pragma unroll
  for (int e = 0; e < 4; ++e) {
    gl_lds16(pA + (size_t)e * 64 * lda, smem + e * 8192 + ldsOff);
    gl_lds16(pB + (size_t)e * 64 * 2048, smem + 32768 + e * 8192 + ldsOff);
  }
  __syncthreads();

  const int NT = 32;
  for (int kt = 0; kt < NT; ++kt) {
    const int cur = (kt & 1) << 16;
    const int nxt = cur ^ 65536;
    // stage kt+1 (issue-early; drained by this tile's end-barrier)
    if (kt + 1 < NT) {
      const int kpos = (kt + 1) * 64;
#pragma unroll
      for (int e = 0; e < 4; ++e) {
        gl_lds16(pA + (size_t)e * 64 * lda + kpos, smem + nxt + e * 8192 + ldsOff);
        gl_lds16(pB + (size_t)e * 64 * 2048 + kpos, smem + nxt + 32768 + e * 8192 + ldsOff);
      }
    }
    // compute current tile: 2 k-subtiles of 32
#pragma unroll
    for (int ksub = 0; ksub < 2; ++ksub) {
      const int so = (((ksub << 2) | lk) ^ laneSwz) << 4;
      bf16x8 bv[4];
#pragma unroll
      for (int ni = 0; ni < 4; ++ni)
        bv[ni] = *(const bf16x8*)(smem + cur + bRow + ni * 2048 + so);
#pragma unroll
      for (int mi = 0; mi < 8; ++mi) {
        bf16x8 av = *(const bf16x8*)(smem + cur + aRow + mi * 2048 + so);
#pragma unroll
        for (int ni = 0; ni < 4; ++ni)
          acc[mi][ni] = __builtin_amdgcn_mfma_f32_16x16x32_bf16(av, bv[ni], acc[mi][ni], 0, 0, 0);
      }
    }
    __syncthreads();
  }

  // ---------------- epilogue (round-3-validated) ----------------
  if (MODE == 0) {
#pragma unroll
    for (int mi = 0; mi < 8; ++mi) {
#pragma unroll
      for (int ni = 0; ni < 4; ++ni) {
        const int rw0 = r0 + wr * 128 + mi * 16 + lk * 4;
        const int cg = m0 + wc * 64 + ni * 16 + lr;
#pragma unroll
        for (int j = 0; j < 4; ++j) {
          const int rw = rw0 + j;
          if (rw < MREAL) Y1out[(size_t)rw * 4096 + cg] = f2bf(acc[mi][ni][j]);
        }
      }
    }
  }

  const int slotBase = (MODE == 0 ? 1 : 2) + 2 * g;
  ushort_t* Tw = (ushort_t*)(smem + wr * 33792);  // [128 cols][132 rows]

#pragma unroll 1
  for (int pass = 0; pass < 2; ++pass) {
    __syncthreads();
    if ((wc >> 1) == pass) {
      const int clb = (wc & 1) * 64;
#pragma unroll
      for (int mi = 0; mi < 8; ++mi) {
        const int rl0 = mi * 16 + lk * 4;
#pragma unroll
        for (int ni = 0; ni < 4; ++ni) {
          const int cl = clb + ni * 16 + lr;
          float v0 = acc[mi][ni][0], v1 = acc[mi][ni][1];
          float v2 = acc[mi][ni][2], v3 = acc[mi][ni][3];
          if (MODE == 1) {
            const size_t xb = (size_t)(r0 + wr * 128 + rl0) * 2048 +
                              ((m0 + pass * 128 + cl) & 2047);
            v0 = 2.f * v0 - bf2f(Xres[xb]);
            v1 = 2.f * v1 - bf2f(Xres[xb + 2048]);
            v2 = 2.f * v2 - bf2f(Xres[xb + 4096]);
            v3 = 2.f * v3 - bf2f(Xres[xb + 6144]);
          }
          ushort4 pk;
          pk.x = f2bf(v0); pk.y = f2bf(v1); pk.z = f2bf(v2); pk.w = f2bf(v3);
          *(ushort4*)&Tw[cl * 132 + rl0] = pk;
        }
      }
    }
    __syncthreads();
#pragma unroll 4
    for (int q = 0; q < 64; ++q) {
      const int idx = q * 512 + tid;
      const int sr = idx >> 14, rem = idx & 16383;
      const int mc = rem >> 7, rl = rem & 127;
      const int rg = r0 + sr * 128 + rl;
      if (rg < MREAL) {
        const unsigned bb = (unsigned)rg / 66u;
        const unsigned ch = (unsigned)rg - bb * 66u;
        const int n = (m0 + pass * 128 + mc) & 2047;
        const ushort_t* Ts = (const ushort_t*)(smem + sr * 33792);
        Ht[((size_t)bb * 2048 + n) * KP + slotBase * 66 + ch] = Ts[mc * 132 + rl];
      }
    }
  }
}

// ---------------- MFMA projection GEMM (round-2 verified) ----------------
template <int MODE>
__global__ __launch_bounds__(256, 2) void proj_mfma(
    const ushort_t* __restrict__ Ht, const ushort_t* __restrict__ Wt,
    const float* __restrict__ bias, const float* __restrict__ hx,
    ushort_t* __restrict__ Xbf, ushort_t* __restrict__ Ubuf,
    float* __restrict__ out) {
  __shared__ ushort_t smem[128 * 130];
  ushort_t* As = smem;
  ushort_t* Bs = smem + 4096;
  const int tid = threadIdx.x;
  const int l = tid & 63, w = tid >> 6;
  const int wr = w >> 1, wc = w & 1;
  const int lr = l & 15, lk = l >> 4;
  const int bb = blockIdx.x >> 4;
  const int n0 = (blockIdx.x & 15) * 128;
  const size_t m0 = (size_t)bb * 2048 + n0;

  f32x4 acc[4][4];
  const f32x4 zero = {0.f, 0.f, 0.f, 0.f};
#pragma unroll
  for (int mi = 0; mi < 4; mi++)
#pragma unroll
    for (int ni = 0; ni < 4; ni++) acc[mi][ni] = zero;

  const int rowA = l >> 2;
  const int kcol = (l & 3) * 8;

  for (int kk = 0; kk < 11; ++kk) {
    const int k0 = kk * 32;
    const int c0 = 2 * w, c1 = 2 * w + 1;
    gl_lds16(Ht + (m0 + c0 * 16 + rowA) * KP + k0 + kcol, (void*)&As[c0 * 512]);
    gl_lds16(Ht + (m0 + c1 * 16 + rowA) * KP + k0 + kcol, (void*)&As[c1 * 512]);
    gl_lds16(Wt + (size_t)(c0 * 16 + rowA) * KP + k0 + kcol, (void*)&Bs[c0 * 512]);
    gl_lds16(Wt + (size_t)(c1 * 16 + rowA) * KP + k0 + kcol, (void*)&Bs[c1 * 512]);
    __syncthreads();

    bf16x8 af[4], bfv[4];
#pragma unroll
    for (int i = 0; i < 4; i++)
      af[i] = *(const bf16x8*)&As[(wr * 64 + i * 16 + lr) * 32 + lk * 8];
#pragma unroll
    for (int i = 0; i < 4; i++)
      bfv[i] = *(const bf16x8*)&Bs[(wc * 64 + i * 16 + lr) * 32 + lk * 8];
#pragma unroll
    for (int mi = 0; mi < 4; mi++)
#pragma unroll
      for (int ni = 0; ni < 4; ni++)
        acc[mi][ni] = __builtin_amdgcn_mfma_f32_16x16x32_bf16(af[mi], bfv[ni], acc[mi][ni], 0, 0, 0);
    __syncthreads();
  }

#pragma unroll
  for (int mi = 0; mi < 4; mi++) {
#pragma unroll
    for (int ni = 0; ni < 4; ni++) {
      const int rl0 = wr * 64 + mi * 16 + lk * 4;
      const int o = wc * 64 + ni * 16 + lr;
      float bv = (MODE == 0 || o < 64) ? bias[o] : 0.f;
#pragma unroll
      for (int j = 0; j < 4; j++) {
        float v = acc[mi][ni][j] + bv;
        float s;
        if (MODE == 0) s = 1.f / (1.f + expf(-v));
        else           s = tanhf(v);
        smem[o * 130 + rl0 + j] = f2bf(s);
      }
    }
  }
  __syncthreads();

  if (MODE == 0) {
#pragma unroll 4
    for (int j2 = 0; j2 < 64; ++j2) {
      int idx = j2 * 256 + tid;
      int o = idx >> 7, m = idx & 127;
      ushort_t sv = smem[o * 130 + m];
      int n = n0 + m;
      if (o < 64) {
        float s = bf2f(sv);
        float hxv = hx[((size_t)bb * 64 + o) * 2048 + n];
        Xbf[((size_t)bb * 66 + 2 + o) * 2048 + n] = f2bf(s * hxv);
      } else {
        Ubuf[((size_t)bb * 64 + (o - 64)) * 2048 + n] = sv;
      }
    }
  } else {
#pragma unroll 4
    for (int j2 = 0; j2 < 32; ++j2) {
      int idx = j2 * 256 + tid;
      int o = idx >> 7, m = idx & 127;
      float Cv = bf2f(smem[o * 130 + m]);
      int n = n0 + m;
      size_t oi = ((size_t)bb * 64 + o) * 2048 + n;
      float u = bf2f(Ubuf[oi]);
      out[oi] = u * hx[oi] + (1.f - u) * Cv;
    }
  }
}

// ---------------- launcher ----------------

extern "C" void kernel_launch(void* const* d_in, const int* in_sizes, int n_in,
                              void* d_out, int out_size, void* d_ws, size_t ws_size,
                              hipStream_t stream) {
  (void)in_sizes; (void)n_in; (void)out_size; (void)ws_size;
  const float* inputs = (const float*)d_in[0];
  const float* hx     = (const float*)d_in[1];
  const float* s0     = (const float*)d_in[2];
  const float* s1     = (const float*)d_in[3];
  const float* W_ru   = (const float*)d_in[4];
  const float* b_ru   = (const float*)d_in[5];
  const float* W_c    = (const float*)d_in[6];
  const float* b_c    = (const float*)d_in[7];
  float* out = (float*)d_out;

  char* p = (char*)d_ws;
  ushort_t* Abf  = (ushort_t*)p; p += (size_t)4096 * 2048 * 2;    // 16.78 MB
  ushort_t* Xbf  = (ushort_t*)p; p += (size_t)4224 * 2048 * 2;    // 17.30 MB
  ushort_t* Y1   = (ushort_t*)p; p += (size_t)4224 * 4096 * 2;    // 34.60 MB
  ushort_t* Ht   = (ushort_t*)p; p += (size_t)MROWS * KP * 2;     // 92.27 MB
  ushort_t* Ubuf = (ushort_t*)p; p += (size_t)64 * 64 * 2048 * 2; // 16.78 MB
  ushort_t* Wtru = (ushort_t*)p; p += (size_t)128 * KP * 2;       // 90 KB
  ushort_t* Wtc  = (ushort_t*)p; p += (size_t)128 * KP * 2;       // 90 KB

  k_cast<<<1024, 256, 0, stream>>>(s0, Abf, 4194304);
  k_cast<<<1024, 256, 0, stream>>>(s1, Abf + 4194304, 4194304);
  k_build_X<<<4224, 256, 0, stream>>>(inputs, hx, Xbf);
  k_pack_W<<<128, 256, 0, stream>>>(W_ru, 128, Wtru);
  k_pack_W<<<128, 256, 0, stream>>>(W_c, 64, Wtc);

  dim3 gt(16, 64);
  // conv 1
  k_trans_slot0<<<gt, 256, 0, stream>>>(Xbf, Ht);
  gemm_bt<0><<<272, 512, 0, stream>>>(Xbf, 2048, Abf, nullptr, Y1, Ht);
  gemm_bt<1><<<272, 512, 0, stream>>>(Y1, 4096, Abf, Xbf, nullptr, Ht);
  proj_mfma<0><<<1024, 256, 0, stream>>>(Ht, Wtru, b_ru, hx, Xbf, Ubuf, nullptr);
  // conv 2
  k_trans_slot0<<<gt, 256, 0, stream>>>(Xbf, Ht);
  gemm_bt<0><<<272, 512, 0, stream>>>(Xbf, 2048, Abf, nullptr, Y1, Ht);
  gemm_bt<1><<<272, 512, 0, stream>>>(Y1, 4096, Abf, Xbf, nullptr, Ht);
  proj_mfma<1><<<1024, 256, 0, stream>>>(Ht, Wtc, b_c, hx, nullptr, Ubuf, out);
}

// Round 5
// 580.854 us; speedup vs baseline: 1.6311x; 1.5972x over previous
//
#include <hip/hip_runtime.h>
#include <stdint.h>

// DCGRU cell on MI355X — round 5: round-2 128^2 GEMM + XCD remap + LDS swizzle.
//
// Buffers (d_ws, ~178 MB, same layout as round 2):
//   Abf  [4096][2048] bf16   supports stacked [A0;A1]
//   Xbf  [4224][2048] bf16   X rows (b*66+c); rows 2..65 overwritten with r*hx
//   Y1   [4224][4096] bf16   x1 (both supports)
//   Ht   [131072][352] bf16  packed H^T: row m=(b*2048+n), col K = slot*66+c
//   Ubuf [64*64*2048] bf16   u gate
//   Wt_ru/Wt_c [128][352] bf16

typedef unsigned short ushort_t;
typedef __attribute__((ext_vector_type(8))) __bf16 bf16x8;
typedef __attribute__((ext_vector_type(4))) float f32x4;

#define KP 352
#define MROWS 131072

__device__ __forceinline__ ushort_t f2bf(float f) {
  union { float f; uint32_t u; } v; v.f = f;
  uint32_t r = v.u + 0x7FFFu + ((v.u >> 16) & 1u);   // RNE
  return (ushort_t)(r >> 16);
}
__device__ __forceinline__ float bf2f(ushort_t u) {
  union { uint32_t u; float f; } v; v.u = ((uint32_t)u) << 16;
  return v.f;
}

__device__ __forceinline__ void gl_lds16(const void* g, void* l) {
  __builtin_amdgcn_global_load_lds(
      (const __attribute__((address_space(1))) void*)g,
      (__attribute__((address_space(3))) void*)l, 16, 0, 0);
}

// ---------------- prep kernels ----------------

__global__ void k_cast(const float* __restrict__ src, ushort_t* __restrict__ dst, int n) {
  for (int i = (blockIdx.x * 256 + threadIdx.x) * 4; i < n; i += gridDim.x * 256 * 4) {
    float4 v = *(const float4*)(src + i);
    ushort4 r;
    r.x = f2bf(v.x); r.y = f2bf(v.y); r.z = f2bf(v.z); r.w = f2bf(v.w);
    *(ushort4*)(dst + i) = r;
  }
}

__global__ void k_build_X(const float* __restrict__ inputs, const float* __restrict__ hx,
                          ushort_t* __restrict__ Xbf) {
  int r = blockIdx.x;
  int b = r / 66, c = r - b * 66;
  const float* src = (c < 2) ? (inputs + ((size_t)b * 2 + c) * 2048)
                             : (hx + ((size_t)b * 64 + (c - 2)) * 2048);
  ushort_t* d1 = Xbf + (size_t)r * 2048;
  for (int n = threadIdx.x * 4; n < 2048; n += 256 * 4) {
    float4 v = *(const float4*)(src + n);
    ushort4 rr;
    rr.x = f2bf(v.x); rr.y = f2bf(v.y); rr.z = f2bf(v.z); rr.w = f2bf(v.w);
    *(ushort4*)(d1 + n) = rr;
  }
}

__global__ void k_pack_W(const float* __restrict__ W, int O, ushort_t* __restrict__ Wt) {
  int o = blockIdx.x;
  for (int k = threadIdx.x; k < KP; k += 256) {
    float v = (k < 330 && o < O) ? W[(size_t)k * O + o] : 0.f;
    Wt[(size_t)o * KP + k] = f2bf(v);
  }
}

// Ht[(b*2048+n)][0..66) = Xbf[(b*66+c)][n]. grid (16, 64)
__global__ __launch_bounds__(256) void k_trans_slot0(const ushort_t* __restrict__ Xbf,
                                                     ushort_t* __restrict__ Ht) {
  __shared__ ushort_t t[66 * 136];
  const int tid = threadIdx.x;
  const int b = blockIdx.y;
  const int n0 = blockIdx.x * 128;
  for (int idx = tid; idx < 66 * 16; idx += 256) {
    int c = idx >> 4, seg = idx & 15;
    bf16x8 v = *(const bf16x8*)&Xbf[((size_t)b * 66 + c) * 2048 + n0 + seg * 8];
    *(bf16x8*)&t[c * 136 + seg * 8] = v;
  }
  __syncthreads();
  for (int idx = tid; idx < 128 * 66; idx += 256) {
    int nn = idx / 66, c = idx - nn * 66;
    Ht[((size_t)b * 2048 + n0 + nn) * KP + c] = t[c * 136 + nn];
  }
}

// ---------------- bf16 MFMA diffusion GEMM (NT, 128x128 tile) ----------------
// C[r,m] = sum_k A[r,k]*B[m,k].  B rows = Abf stacked (row m in [0,4096)).
// MODE 0: writes Y1out[r][m] and Ht slot (1+2g).
// MODE 1: A offset g*2048; Ht slot (2+2g) = bf16(2*C - Xres[r][m&2047]).
// New vs round 2:
//  - bijective XCD remap: fid%8 owns nb in [xcd*4, xcd*4+4) sweeping mb
//    (B-panels 2MB L2-resident per XCD; measured-class FETCH reduction).
//  - both-sides LDS slot swizzle: LDS slot s of row r holds global k-slot
//    s ^ ((r>>1)&3) (pre-swizzled global src, linear LDS dest); reads XOR
//    the same mask. Kills rows-2-apart bank aliasing; residual 2-way free.
template <int MODE>
__global__ __launch_bounds__(256, 2) void gemm_bt(
    const ushort_t* __restrict__ Aop, int lda,
    const ushort_t* __restrict__ Bop,
    const ushort_t* __restrict__ Xres,
    ushort_t* __restrict__ Y1out,
    ushort_t* __restrict__ Ht) {
  __shared__ ushort_t smem[128 * 130];   // As[0..4096) Bs[4096..8192); epilogue: cTile
  ushort_t* As = smem;
  ushort_t* Bs = smem + 4096;
  const int tid = threadIdx.x;
  const int l = tid & 63, w = tid >> 6;
  const int wr = w >> 1, wc = w & 1;
  const int lr = l & 15, lk = l >> 4;

  // XCD-aware bijective remap (1056 = 8 * 132; 132 = 4 nb * 33 mb)
  const int fid = blockIdx.y * 33 + blockIdx.x;
  const int xcd = fid & 7;
  const int idx = fid >> 3;            // 0..131
  const int nb = xcd * 4 + idx / 33;
  const int mb = idx % 33;
  const int r0 = mb * 128;
  const int m0 = nb * 128;
  const int g = m0 >> 11;
  if (MODE == 1) Aop += (size_t)g * 2048;

  f32x4 acc[4][4];
  const f32x4 zero = {0.f, 0.f, 0.f, 0.f};
#pragma unroll
  for (int mi = 0; mi < 4; mi++)
#pragma unroll
    for (int ni = 0; ni < 4; ni++) acc[mi][ni] = zero;

  const int rowA = l >> 2;                                   // row within 16-row chunk
  const int kcol = (((l & 3) ^ ((l >> 3) & 3)) * 8);         // pre-swizzled k-slot
  const int sSwz = (lr >> 1) & 3;                            // read-side slot XOR

  for (int kk = 0; kk < 64; ++kk) {
    const int k0 = kk * 32;
    const int c0 = 2 * w, c1 = 2 * w + 1;
    gl_lds16(Aop + (size_t)(r0 + c0 * 16 + rowA) * lda + k0 + kcol, (void*)&As[c0 * 512]);
    gl_lds16(Aop + (size_t)(r0 + c1 * 16 + rowA) * lda + k0 + kcol, (void*)&As[c1 * 512]);
    gl_lds16(Bop + (size_t)(m0 + c0 * 16 + rowA) * 2048 + k0 + kcol, (void*)&Bs[c0 * 512]);
    gl_lds16(Bop + (size_t)(m0 + c1 * 16 + rowA) * 2048 + k0 + kcol, (void*)&Bs[c1 * 512]);
    __syncthreads();

    bf16x8 af[4], bfv[4];
    const int so = (lk ^ sSwz) * 8;
#pragma unroll
    for (int i = 0; i < 4; i++)
      af[i] = *(const bf16x8*)&As[(wr * 64 + i * 16 + lr) * 32 + so];
#pragma unroll
    for (int i = 0; i < 4; i++)
      bfv[i] = *(const bf16x8*)&Bs[(wc * 64 + i * 16 + lr) * 32 + so];
#pragma unroll
    for (int mi = 0; mi < 4; mi++)
#pragma unroll
      for (int ni = 0; ni < 4; ni++)
        acc[mi][ni] = __builtin_amdgcn_mfma_f32_16x16x32_bf16(af[mi], bfv[ni], acc[mi][ni], 0, 0, 0);
    __syncthreads();
  }

  // epilogue: optional Y1 direct store + bf16 value into transposed LDS tile
#pragma unroll
  for (int mi = 0; mi < 4; mi++) {
#pragma unroll
    for (int ni = 0; ni < 4; ni++) {
      const int rl0 = wr * 64 + mi * 16 + lk * 4;
      const int cl = wc * 64 + ni * 16 + lr;
      const int col = m0 + cl;
#pragma unroll
      for (int j = 0; j < 4; j++) {
        float v = acc[mi][ni][j];
        if (MODE == 1)
          v = 2.f * v - bf2f(Xres[(size_t)(r0 + rl0 + j) * 2048 + (col & 2047)]);
        ushort_t bv = f2bf(v);
        if (MODE == 0) Y1out[(size_t)(r0 + rl0 + j) * 4096 + col] = bv;
        smem[cl * 130 + rl0 + j] = bv;
      }
    }
  }
  __syncthreads();

  // transposed write into Ht: row m=(b*2048+n), col = slot*66 + c
  const int slotBase = (MODE == 0 ? 1 : 2) + 2 * g;
  const int n_base = m0 & 2047;
#pragma unroll 4
  for (int j2 = 0; j2 < 64; ++j2) {
    int idx2 = j2 * 256 + tid;
    int mc = idx2 >> 7, rl = idx2 & 127;
    unsigned rg = (unsigned)(r0 + rl);
    unsigned b = rg / 66u;
    unsigned c = rg - b * 66u;
    int n = n_base + mc;
    Ht[((size_t)b * 2048 + n) * KP + slotBase * 66 + c] = smem[mc * 130 + rl];
  }
}

// ---------------- MFMA projection GEMM (round-2 verified) ----------------
template <int MODE>
__global__ __launch_bounds__(256, 2) void proj_mfma(
    const ushort_t* __restrict__ Ht, const ushort_t* __restrict__ Wt,
    const float* __restrict__ bias, const float* __restrict__ hx,
    ushort_t* __restrict__ Xbf, ushort_t* __restrict__ Ubuf,
    float* __restrict__ out) {
  __shared__ ushort_t smem[128 * 130];
  ushort_t* As = smem;
  ushort_t* Bs = smem + 4096;
  const int tid = threadIdx.x;
  const int l = tid & 63, w = tid >> 6;
  const int wr = w >> 1, wc = w & 1;
  const int lr = l & 15, lk = l >> 4;
  const int bb = blockIdx.x >> 4;
  const int n0 = (blockIdx.x & 15) * 128;
  const size_t m0 = (size_t)bb * 2048 + n0;

  f32x4 acc[4][4];
  const f32x4 zero = {0.f, 0.f, 0.f, 0.f};
#pragma unroll
  for (int mi = 0; mi < 4; mi++)
#pragma unroll
    for (int ni = 0; ni < 4; ni++) acc[mi][ni] = zero;

  const int rowA = l >> 2;
  const int kcol = (l & 3) * 8;

  for (int kk = 0; kk < 11; ++kk) {
    const int k0 = kk * 32;
    const int c0 = 2 * w, c1 = 2 * w + 1;
    gl_lds16(Ht + (m0 + c0 * 16 + rowA) * KP + k0 + kcol, (void*)&As[c0 * 512]);
    gl_lds16(Ht + (m0 + c1 * 16 + rowA) * KP + k0 + kcol, (void*)&As[c1 * 512]);
    gl_lds16(Wt + (size_t)(c0 * 16 + rowA) * KP + k0 + kcol, (void*)&Bs[c0 * 512]);
    gl_lds16(Wt + (size_t)(c1 * 16 + rowA) * KP + k0 + kcol, (void*)&Bs[c1 * 512]);
    __syncthreads();

    bf16x8 af[4], bfv[4];
#pragma unroll
    for (int i = 0; i < 4; i++)
      af[i] = *(const bf16x8*)&As[(wr * 64 + i * 16 + lr) * 32 + lk * 8];
#pragma unroll
    for (int i = 0; i < 4; i++)
      bfv[i] = *(const bf16x8*)&Bs[(wc * 64 + i * 16 + lr) * 32 + lk * 8];
#pragma unroll
    for (int mi = 0; mi < 4; mi++)
#pragma unroll
      for (int ni = 0; ni < 4; ni++)
        acc[mi][ni] = __builtin_amdgcn_mfma_f32_16x16x32_bf16(af[mi], bfv[ni], acc[mi][ni], 0, 0, 0);
    __syncthreads();
  }

#pragma unroll
  for (int mi = 0; mi < 4; mi++) {
#pragma unroll
    for (int ni = 0; ni < 4; ni++) {
      const int rl0 = wr * 64 + mi * 16 + lk * 4;
      const int o = wc * 64 + ni * 16 + lr;
      float bv = (MODE == 0 || o < 64) ? bias[o] : 0.f;
#pragma unroll
      for (int j = 0; j < 4; j++) {
        float v = acc[mi][ni][j] + bv;
        float s;
        if (MODE == 0) s = 1.f / (1.f + expf(-v));
        else           s = tanhf(v);
        smem[o * 130 + rl0 + j] = f2bf(s);
      }
    }
  }
  __syncthreads();

  if (MODE == 0) {
#pragma unroll 4
    for (int j2 = 0; j2 < 64; ++j2) {
      int idx = j2 * 256 + tid;
      int o = idx >> 7, m = idx & 127;
      ushort_t sv = smem[o * 130 + m];
      int n = n0 + m;
      if (o < 64) {
        float s = bf2f(sv);
        float hxv = hx[((size_t)bb * 64 + o) * 2048 + n];
        Xbf[((size_t)bb * 66 + 2 + o) * 2048 + n] = f2bf(s * hxv);
      } else {
        Ubuf[((size_t)bb * 64 + (o - 64)) * 2048 + n] = sv;
      }
    }
  } else {
#pragma unroll 4
    for (int j2 = 0; j2 < 32; ++j2) {
      int idx = j2 * 256 + tid;
      int o = idx >> 7, m = idx & 127;
      float Cv = bf2f(smem[o * 130 + m]);
      int n = n0 + m;
      size_t oi = ((size_t)bb * 64 + o) * 2048 + n;
      float u = bf2f(Ubuf[oi]);
      out[oi] = u * hx[oi] + (1.f - u) * Cv;
    }
  }
}

// ---------------- launcher ----------------

extern "C" void kernel_launch(void* const* d_in, const int* in_sizes, int n_in,
                              void* d_out, int out_size, void* d_ws, size_t ws_size,
                              hipStream_t stream) {
  (void)in_sizes; (void)n_in; (void)out_size; (void)ws_size;
  const float* inputs = (const float*)d_in[0];
  const float* hx     = (const float*)d_in[1];
  const float* s0     = (const float*)d_in[2];
  const float* s1     = (const float*)d_in[3];
  const float* W_ru   = (const float*)d_in[4];
  const float* b_ru   = (const float*)d_in[5];
  const float* W_c    = (const float*)d_in[6];
  const float* b_c    = (const float*)d_in[7];
  float* out = (float*)d_out;

  char* p = (char*)d_ws;
  ushort_t* Abf  = (ushort_t*)p; p += (size_t)4096 * 2048 * 2;    // 16.78 MB
  ushort_t* Xbf  = (ushort_t*)p; p += (size_t)4224 * 2048 * 2;    // 17.30 MB
  ushort_t* Y1   = (ushort_t*)p; p += (size_t)4224 * 4096 * 2;    // 34.60 MB
  ushort_t* Ht   = (ushort_t*)p; p += (size_t)MROWS * KP * 2;     // 92.27 MB
  ushort_t* Ubuf = (ushort_t*)p; p += (size_t)64 * 64 * 2048 * 2; // 16.78 MB
  ushort_t* Wtru = (ushort_t*)p; p += (size_t)128 * KP * 2;       // 90 KB
  ushort_t* Wtc  = (ushort_t*)p; p += (size_t)128 * KP * 2;       // 90 KB

  k_cast<<<1024, 256, 0, stream>>>(s0, Abf, 4194304);
  k_cast<<<1024, 256, 0, stream>>>(s1, Abf + 4194304, 4194304);
  k_build_X<<<4224, 256, 0, stream>>>(inputs, hx, Xbf);
  k_pack_W<<<128, 256, 0, stream>>>(W_ru, 128, Wtru);
  k_pack_W<<<128, 256, 0, stream>>>(W_c, 64, Wtc);

  dim3 g(33, 32);
  dim3 gt(16, 64);
  // conv 1
  k_trans_slot0<<<gt, 256, 0, stream>>>(Xbf, Ht);
  gemm_bt<0><<<g, 256, 0, stream>>>(Xbf, 2048, Abf, nullptr, Y1, Ht);
  gemm_bt<1><<<g, 256, 0, stream>>>(Y1, 4096, Abf, Xbf, nullptr, Ht);
  proj_mfma<0><<<1024, 256, 0, stream>>>(Ht, Wtru, b_ru, hx, Xbf, Ubuf, nullptr);
  // conv 2
  k_trans_slot0<<<gt, 256, 0, stream>>>(Xbf, Ht);
  gemm_bt<0><<<g, 256, 0, stream>>>(Xbf, 2048, Abf, nullptr, Y1, Ht);
  gemm_bt<1><<<g, 256, 0, stream>>>(Y1, 4096, Abf, Xbf, nullptr, Ht);
  proj_mfma<1><<<1024, 256, 0, stream>>>(Ht, Wtc, b_c, hx, nullptr, Ubuf, out);
}

// Round 6
// 513.979 us; speedup vs baseline: 1.8433x; 1.1301x over previous
//
#include <hip/hip_runtime.h>
#include <stdint.h>

// DCGRU cell on MI355X — round 6: BK=64 (half the barriers) + 4 blocks/CU.
//
// Buffers (d_ws, ~178 MB, same layout as round 2):
//   Abf  [4096][2048] bf16   supports stacked [A0;A1]
//   Xbf  [4224][2048] bf16   X rows (b*66+c); rows 2..65 overwritten with r*hx
//   Y1   [4224][4096] bf16   x1 (both supports)
//   Ht   [131072][352] bf16  packed H^T: row m=(b*2048+n), col K = slot*66+c
//   Ubuf [64*64*2048] bf16   u gate
//   Wt_ru/Wt_c [128][352] bf16

typedef unsigned short ushort_t;
typedef __attribute__((ext_vector_type(8))) __bf16 bf16x8;
typedef __attribute__((ext_vector_type(4))) float f32x4;

#define KP 352
#define MROWS 131072

__device__ __forceinline__ ushort_t f2bf(float f) {
  union { float f; uint32_t u; } v; v.f = f;
  uint32_t r = v.u + 0x7FFFu + ((v.u >> 16) & 1u);   // RNE
  return (ushort_t)(r >> 16);
}
__device__ __forceinline__ float bf2f(ushort_t u) {
  union { uint32_t u; float f; } v; v.u = ((uint32_t)u) << 16;
  return v.f;
}

__device__ __forceinline__ void gl_lds16(const void* g, void* l) {
  __builtin_amdgcn_global_load_lds(
      (const __attribute__((address_space(1))) void*)g,
      (__attribute__((address_space(3))) void*)l, 16, 0, 0);
}

// ---------------- prep kernels ----------------

__global__ void k_cast(const float* __restrict__ src, ushort_t* __restrict__ dst, int n) {
  for (int i = (blockIdx.x * 256 + threadIdx.x) * 4; i < n; i += gridDim.x * 256 * 4) {
    float4 v = *(const float4*)(src + i);
    ushort4 r;
    r.x = f2bf(v.x); r.y = f2bf(v.y); r.z = f2bf(v.z); r.w = f2bf(v.w);
    *(ushort4*)(dst + i) = r;
  }
}

__global__ void k_build_X(const float* __restrict__ inputs, const float* __restrict__ hx,
                          ushort_t* __restrict__ Xbf) {
  int r = blockIdx.x;
  int b = r / 66, c = r - b * 66;
  const float* src = (c < 2) ? (inputs + ((size_t)b * 2 + c) * 2048)
                             : (hx + ((size_t)b * 64 + (c - 2)) * 2048);
  ushort_t* d1 = Xbf + (size_t)r * 2048;
  for (int n = threadIdx.x * 4; n < 2048; n += 256 * 4) {
    float4 v = *(const float4*)(src + n);
    ushort4 rr;
    rr.x = f2bf(v.x); rr.y = f2bf(v.y); rr.z = f2bf(v.z); rr.w = f2bf(v.w);
    *(ushort4*)(d1 + n) = rr;
  }
}

__global__ void k_pack_W(const float* __restrict__ W, int O, ushort_t* __restrict__ Wt) {
  int o = blockIdx.x;
  for (int k = threadIdx.x; k < KP; k += 256) {
    float v = (k < 330 && o < O) ? W[(size_t)k * O + o] : 0.f;
    Wt[(size_t)o * KP + k] = f2bf(v);
  }
}

// Ht[(b*2048+n)][0..66) = Xbf[(b*66+c)][n]. grid (16, 64)
__global__ __launch_bounds__(256) void k_trans_slot0(const ushort_t* __restrict__ Xbf,
                                                     ushort_t* __restrict__ Ht) {
  __shared__ ushort_t t[66 * 136];
  const int tid = threadIdx.x;
  const int b = blockIdx.y;
  const int n0 = blockIdx.x * 128;
  for (int idx = tid; idx < 66 * 16; idx += 256) {
    int c = idx >> 4, seg = idx & 15;
    bf16x8 v = *(const bf16x8*)&Xbf[((size_t)b * 66 + c) * 2048 + n0 + seg * 8];
    *(bf16x8*)&t[c * 136 + seg * 8] = v;
  }
  __syncthreads();
  for (int idx = tid; idx < 128 * 66; idx += 256) {
    int nn = idx / 66, c = idx - nn * 66;
    Ht[((size_t)b * 2048 + n0 + nn) * KP + c] = t[c * 136 + nn];
  }
}

// ---------------- bf16 MFMA diffusion GEMM (NT, 128x128 tile, BK=64) ----------------
// C[r,m] = sum_k A[r,k]*B[m,k].  B rows = Abf stacked (row m in [0,4096)).
// MODE 0: writes Y1out[r][m] and Ht slot (1+2g).
// MODE 1: A offset g*2048; Ht slot (2+2g) = bf16(2*C - Xres[r][m&2047]).
// vs round 5: BK 32->64 (32 K-steps, 32 MFMA per barrier pair — halves the
// barrier/drain overhead), 4 blocks/CU (launch_bounds(256,4); 60+64 regs fits
// the 128-reg budget, LDS 33.3KB x 4 = 133KB).
// LDS: As [128 rows][8 k-slots of 16B], Bs likewise; slot s of row r holds
// global k-slot s^(r&7) (pre-swizzled global source, linear LDS dest); reads
// XOR the same mask -> residual 2-way bank aliasing (free).
template <int MODE>
__global__ __launch_bounds__(256, 4) void gemm_bt(
    const ushort_t* __restrict__ Aop, int lda,
    const ushort_t* __restrict__ Bop,
    const ushort_t* __restrict__ Xres,
    ushort_t* __restrict__ Y1out,
    ushort_t* __restrict__ Ht) {
  __shared__ ushort_t smem[128 * 130];   // K-loop: As[0..8192) Bs[8192..16384); epilogue: cTile
  ushort_t* As = smem;
  ushort_t* Bs = smem + 8192;
  const int tid = threadIdx.x;
  const int l = tid & 63, w = tid >> 6;
  const int wr = w >> 1, wc = w & 1;
  const int lr = l & 15, lk = l >> 4;

  // XCD-aware bijective remap (1056 = 8 * 132; 132 = 4 nb * 33 mb)
  const int fid = blockIdx.y * 33 + blockIdx.x;
  const int xcd = fid & 7;
  const int idx = fid >> 3;            // 0..131
  const int nb = xcd * 4 + idx / 33;
  const int mb = idx % 33;
  const int r0 = mb * 128;
  const int m0 = nb * 128;
  const int g = m0 >> 11;
  if (MODE == 1) Aop += (size_t)g * 2048;

  f32x4 acc[4][4];
  const f32x4 zero = {0.f, 0.f, 0.f, 0.f};
#pragma unroll
  for (int mi = 0; mi < 4; mi++)
#pragma unroll
    for (int ni = 0; ni < 4; ni++) acc[mi][ni] = zero;

  // staging lane constants: thread t stages row (t>>3), k-slot (t&7) of each
  // 32-row chunk; global k pre-swizzled so LDS dest stays linear.
  const int srow = tid >> 3;                              // 0..31
  const int kcol = ((tid & 7) ^ (srow & 7)) * 8;          // pre-swizzled k elems
  const int sSwz = lr & 7;                                // read-side slot XOR

  for (int kk = 0; kk < 32; ++kk) {
    const int k0 = kk * 64;
#pragma unroll
    for (int e = 0; e < 4; ++e) {
      gl_lds16(Aop + (size_t)(r0 + e * 32 + srow) * lda + k0 + kcol, (void*)&As[e * 2048 + tid * 8]);
      gl_lds16(Bop + (size_t)(m0 + e * 32 + srow) * 2048 + k0 + kcol, (void*)&Bs[e * 2048 + tid * 8]);
    }
    __syncthreads();

#pragma unroll
    for (int ksub = 0; ksub < 2; ++ksub) {
      const int so = ((ksub * 4 + lk) ^ sSwz) * 8;
      bf16x8 af[4], bfv[4];
#pragma unroll
      for (int i = 0; i < 4; i++)
        af[i] = *(const bf16x8*)&As[(wr * 64 + i * 16 + lr) * 64 + so];
#pragma unroll
      for (int i = 0; i < 4; i++)
        bfv[i] = *(const bf16x8*)&Bs[(wc * 64 + i * 16 + lr) * 64 + so];
#pragma unroll
      for (int mi = 0; mi < 4; mi++)
#pragma unroll
        for (int ni = 0; ni < 4; ni++)
          acc[mi][ni] = __builtin_amdgcn_mfma_f32_16x16x32_bf16(af[mi], bfv[ni], acc[mi][ni], 0, 0, 0);
    }
    __syncthreads();
  }

  // epilogue: optional Y1 direct store + bf16 value into transposed LDS tile
#pragma unroll
  for (int mi = 0; mi < 4; mi++) {
#pragma unroll
    for (int ni = 0; ni < 4; ni++) {
      const int rl0 = wr * 64 + mi * 16 + lk * 4;
      const int cl = wc * 64 + ni * 16 + lr;
      const int col = m0 + cl;
#pragma unroll
      for (int j = 0; j < 4; j++) {
        float v = acc[mi][ni][j];
        if (MODE == 1)
          v = 2.f * v - bf2f(Xres[(size_t)(r0 + rl0 + j) * 2048 + (col & 2047)]);
        ushort_t bv = f2bf(v);
        if (MODE == 0) Y1out[(size_t)(r0 + rl0 + j) * 4096 + col] = bv;
        smem[cl * 130 + rl0 + j] = bv;
      }
    }
  }
  __syncthreads();

  // transposed write into Ht: row m=(b*2048+n), col = slot*66 + c
  const int slotBase = (MODE == 0 ? 1 : 2) + 2 * g;
  const int n_base = m0 & 2047;
#pragma unroll 4
  for (int j2 = 0; j2 < 64; ++j2) {
    int idx2 = j2 * 256 + tid;
    int mc = idx2 >> 7, rl = idx2 & 127;
    unsigned rg = (unsigned)(r0 + rl);
    unsigned b = rg / 66u;
    unsigned c = rg - b * 66u;
    int n = n_base + mc;
    Ht[((size_t)b * 2048 + n) * KP + slotBase * 66 + c] = smem[mc * 130 + rl];
  }
}

// ---------------- MFMA projection GEMM (round-2 verified) ----------------
template <int MODE>
__global__ __launch_bounds__(256, 2) void proj_mfma(
    const ushort_t* __restrict__ Ht, const ushort_t* __restrict__ Wt,
    const float* __restrict__ bias, const float* __restrict__ hx,
    ushort_t* __restrict__ Xbf, ushort_t* __restrict__ Ubuf,
    float* __restrict__ out) {
  __shared__ ushort_t smem[128 * 130];
  ushort_t* As = smem;
  ushort_t* Bs = smem + 4096;
  const int tid = threadIdx.x;
  const int l = tid & 63, w = tid >> 6;
  const int wr = w >> 1, wc = w & 1;
  const int lr = l & 15, lk = l >> 4;
  const int bb = blockIdx.x >> 4;
  const int n0 = (blockIdx.x & 15) * 128;
  const size_t m0 = (size_t)bb * 2048 + n0;

  f32x4 acc[4][4];
  const f32x4 zero = {0.f, 0.f, 0.f, 0.f};
#pragma unroll
  for (int mi = 0; mi < 4; mi++)
#pragma unroll
    for (int ni = 0; ni < 4; ni++) acc[mi][ni] = zero;

  const int rowA = l >> 2;
  const int kcol = (l & 3) * 8;

  for (int kk = 0; kk < 11; ++kk) {
    const int k0 = kk * 32;
    const int c0 = 2 * w, c1 = 2 * w + 1;
    gl_lds16(Ht + (m0 + c0 * 16 + rowA) * KP + k0 + kcol, (void*)&As[c0 * 512]);
    gl_lds16(Ht + (m0 + c1 * 16 + rowA) * KP + k0 + kcol, (void*)&As[c1 * 512]);
    gl_lds16(Wt + (size_t)(c0 * 16 + rowA) * KP + k0 + kcol, (void*)&Bs[c0 * 512]);
    gl_lds16(Wt + (size_t)(c1 * 16 + rowA) * KP + k0 + kcol, (void*)&Bs[c1 * 512]);
    __syncthreads();

    bf16x8 af[4], bfv[4];
#pragma unroll
    for (int i = 0; i < 4; i++)
      af[i] = *(const bf16x8*)&As[(wr * 64 + i * 16 + lr) * 32 + lk * 8];
#pragma unroll
    for (int i = 0; i < 4; i++)
      bfv[i] = *(const bf16x8*)&Bs[(wc * 64 + i * 16 + lr) * 32 + lk * 8];
#pragma unroll
    for (int mi = 0; mi < 4; mi++)
#pragma unroll
      for (int ni = 0; ni < 4; ni++)
        acc[mi][ni] = __builtin_amdgcn_mfma_f32_16x16x32_bf16(af[mi], bfv[ni], acc[mi][ni], 0, 0, 0);
    __syncthreads();
  }

#pragma unroll
  for (int mi = 0; mi < 4; mi++) {
#pragma unroll
    for (int ni = 0; ni < 4; ni++) {
      const int rl0 = wr * 64 + mi * 16 + lk * 4;
      const int o = wc * 64 + ni * 16 + lr;
      float bv = (MODE == 0 || o < 64) ? bias[o] : 0.f;
#pragma unroll
      for (int j = 0; j < 4; j++) {
        float v = acc[mi][ni][j] + bv;
        float s;
        if (MODE == 0) s = 1.f / (1.f + expf(-v));
        else           s = tanhf(v);
        smem[o * 130 + rl0 + j] = f2bf(s);
      }
    }
  }
  __syncthreads();

  if (MODE == 0) {
#pragma unroll 4
    for (int j2 = 0; j2 < 64; ++j2) {
      int idx = j2 * 256 + tid;
      int o = idx >> 7, m = idx & 127;
      ushort_t sv = smem[o * 130 + m];
      int n = n0 + m;
      if (o < 64) {
        float s = bf2f(sv);
        float hxv = hx[((size_t)bb * 64 + o) * 2048 + n];
        Xbf[((size_t)bb * 66 + 2 + o) * 2048 + n] = f2bf(s * hxv);
      } else {
        Ubuf[((size_t)bb * 64 + (o - 64)) * 2048 + n] = sv;
      }
    }
  } else {
#pragma unroll 4
    for (int j2 = 0; j2 < 32; ++j2) {
      int idx = j2 * 256 + tid;
      int o = idx >> 7, m = idx & 127;
      float Cv = bf2f(smem[o * 130 + m]);
      int n = n0 + m;
      size_t oi = ((size_t)bb * 64 + o) * 2048 + n;
      float u = bf2f(Ubuf[oi]);
      out[oi] = u * hx[oi] + (1.f - u) * Cv;
    }
  }
}

// ---------------- launcher ----------------

extern "C" void kernel_launch(void* const* d_in, const int* in_sizes, int n_in,
                              void* d_out, int out_size, void* d_ws, size_t ws_size,
                              hipStream_t stream) {
  (void)in_sizes; (void)n_in; (void)out_size; (void)ws_size;
  const float* inputs = (const float*)d_in[0];
  const float* hx     = (const float*)d_in[1];
  const float* s0     = (const float*)d_in[2];
  const float* s1     = (const float*)d_in[3];
  const float* W_ru   = (const float*)d_in[4];
  const float* b_ru   = (const float*)d_in[5];
  const float* W_c    = (const float*)d_in[6];
  const float* b_c    = (const float*)d_in[7];
  float* out = (float*)d_out;

  char* p = (char*)d_ws;
  ushort_t* Abf  = (ushort_t*)p; p += (size_t)4096 * 2048 * 2;    // 16.78 MB
  ushort_t* Xbf  = (ushort_t*)p; p += (size_t)4224 * 2048 * 2;    // 17.30 MB
  ushort_t* Y1   = (ushort_t*)p; p += (size_t)4224 * 4096 * 2;    // 34.60 MB
  ushort_t* Ht   = (ushort_t*)p; p += (size_t)MROWS * KP * 2;     // 92.27 MB
  ushort_t* Ubuf = (ushort_t*)p; p += (size_t)64 * 64 * 2048 * 2; // 16.78 MB
  ushort_t* Wtru = (ushort_t*)p; p += (size_t)128 * KP * 2;       // 90 KB
  ushort_t* Wtc  = (ushort_t*)p; p += (size_t)128 * KP * 2;       // 90 KB

  k_cast<<<1024, 256, 0, stream>>>(s0, Abf, 4194304);
  k_cast<<<1024, 256, 0, stream>>>(s1, Abf + 4194304, 4194304);
  k_build_X<<<4224, 256, 0, stream>>>(inputs, hx, Xbf);
  k_pack_W<<<128, 256, 0, stream>>>(W_ru, 128, Wtru);
  k_pack_W<<<128, 256, 0, stream>>>(W_c, 64, Wtc);

  dim3 g(33, 32);
  dim3 gt(16, 64);
  // conv 1
  k_trans_slot0<<<gt, 256, 0, stream>>>(Xbf, Ht);
  gemm_bt<0><<<g, 256, 0, stream>>>(Xbf, 2048, Abf, nullptr, Y1, Ht);
  gemm_bt<1><<<g, 256, 0, stream>>>(Y1, 4096, Abf, Xbf, nullptr, Ht);
  proj_mfma<0><<<1024, 256, 0, stream>>>(Ht, Wtru, b_ru, hx, Xbf, Ubuf, nullptr);
  // conv 2
  k_trans_slot0<<<gt, 256, 0, stream>>>(Xbf, Ht);
  gemm_bt<0><<<g, 256, 0, stream>>>(Xbf, 2048, Abf, nullptr, Y1, Ht);
  gemm_bt<1><<<g, 256, 0, stream>>>(Y1, 4096, Abf, Xbf, nullptr, Ht);
  proj_mfma<1><<<1024, 256, 0, stream>>>(Ht, Wtc, b_c, hx, nullptr, Ubuf, out);
}